// Round 9
// baseline (115.255 us; speedup 1.0000x reference)
//
#include <hip/hip_runtime.h>
#include <math.h>

// Problem constants (fixed by the reference): B=8, C=3, K=4, H=512, W=512
// HW = 262144. Total pixels = B*C*HW = 6291456 = 24576 * 256 exactly.
// Scalar kernel: 1 pixel per thread -> minimal register state, max occupancy
// (8 waves/SIMD). Wave loads are 64 lanes x 4B = 256B per stream, coalesced.
// Best measured configuration (round 7: 112.4 us = 92.5% of copy ceiling).

#define HALF_LOG2E 0.7213475204444817f   // log2(e)/2
#define HW 262144

__global__ void gmm_kernel(
    const float* __restrict__ x_,
    const float* __restrict__ U_,
    const float* __restrict__ V_,
    const float* __restrict__ N_,
    const float* __restrict__ eta_p,
    float* __restrict__ out,
    int ckhw)       // B*C*K*HW = one output tensor in floats
{
    const int p  = blockIdx.x * 256 + threadIdx.x;   // pixel id, grid exact
    const int bc = p >> 18;                          // (b*C + c)
    const int off = p & (HW - 1);
    const int base = bc * 4 * HW + off;              // plane (bc*K+k), k stride = HW

    const float nTotal = 1.0f / eta_p[0] - 1.0f;     // 99

    float* Uo = out;
    float* Vo = Uo + ckhw;
    float* No = Vo + ckhw;
    float* Po = No + ckhw;

    // ---- loads: 13 coalesced scalar streams ----
    const float xs = x_[p];
    float u[4], vv[4], nn[4];
#pragma unroll
    for (int k = 0; k < 4; ++k) {
        u[k]  = U_[base + k * HW];
        vv[k] = V_[base + k * HW];
        nn[k] = N_[base + k * HW];
    }

    float nsum = (nn[0] + nn[1]) + (nn[2] + nn[3]);
    const float inv_nsum = __builtin_amdgcn_rcpf(nsum);

    // Abramowitz-Stegun 7.1.26, pre-halved: 0.5*(1+erf(y)) = 1 - polyh(t)*exp(-y^2)
    const float pC  = 0.3275911f;
    const float a1h = 0.254829592f * 0.5f;
    const float a2h = -0.284496736f * 0.5f;
    const float a3h = 1.421413741f * 0.5f;
    const float a4h = -1.453152027f * 0.5f;
    const float a5h = 1.061405429f * 0.5f;

    // base-2 logits: l2 = log2(Nn*invS) - zz, zz = log2(e)/2 * z^2
    float l2[4], Nn[4], Xd[4];
    float prob = 0.f;
    float m = -1e30f;
#pragma unroll
    for (int k = 0; k < 4; ++k) {
        const float uu   = u[k];
        const float s2   = fmaxf(vv[k] - uu * uu, 0.01f);
        const float invS = __builtin_amdgcn_rsqf(s2);
        const float xd   = xs - uu;
        const float z    = xd * invS;
        const float zz   = HALF_LOG2E * z * z;
        const float P    = nn[k] * inv_nsum;        // Nn / nTotal
        const float nnk  = nTotal * P;              // Nn

        const float y    = fabsf(z) * 0.70710678118654752440f;
        const float tt   = __builtin_amdgcn_rcpf(fmaf(pC, y, 1.0f));
        const float e    = __builtin_amdgcn_exp2f(-zz);
        float poly = fmaf(a5h, tt, a4h);
        poly = fmaf(poly, tt, a3h);
        poly = fmaf(poly, tt, a2h);
        poly = fmaf(poly, tt, a1h);
        poly = poly * tt;
        const float cdf  = fmaf(-poly, e, 1.0f);
        prob = fmaf(P, cdf, prob);

        const float l = __builtin_amdgcn_logf(nnk * invS) - zz;
        l2[k] = l;
        m = fmaxf(m, l);
        Nn[k] = nnk;
        Xd[k] = xd;
    }

    float g[4];
#pragma unroll
    for (int k = 0; k < 4; ++k) g[k] = __builtin_amdgcn_exp2f(l2[k] - m);
    const float gs = (g[0] + g[1]) + (g[2] + g[3]);
    const float invgs = __builtin_amdgcn_rcpf(gs);
    const float x2 = xs * xs;

#pragma unroll
    for (int k = 0; k < 4; ++k) {
        const float Gamma = g[k] * invgs;
        const float Nout  = Nn[k] + Gamma;
        const float Eta   = Gamma * __builtin_amdgcn_rcpf(Nout);
        __builtin_nontemporal_store(u[k]  + Eta * Xd[k],        &Uo[base + k * HW]);
        __builtin_nontemporal_store(vv[k] + Eta * (x2 - vv[k]), &Vo[base + k * HW]);
        __builtin_nontemporal_store(Nout,                        &No[base + k * HW]);
    }
    __builtin_nontemporal_store(prob, &Po[p]);
}

extern "C" void kernel_launch(void* const* d_in, const int* in_sizes, int n_in,
                              void* d_out, int out_size, void* d_ws, size_t ws_size,
                              hipStream_t stream) {
    const float* x  = (const float*)d_in[0];
    const float* U  = (const float*)d_in[1];
    const float* V  = (const float*)d_in[2];
    const float* N  = (const float*)d_in[3];
    const float* eta = (const float*)d_in[4];
    float* out = (float*)d_out;

    const int totalPix = in_sizes[0];    // 6291456
    const int ckhw     = in_sizes[1];    // 25165824

    const int block = 256;
    const int grid  = totalPix / block;  // 24576, exact
    gmm_kernel<<<grid, block, 0, stream>>>(x, U, V, N, eta, out, ckhw);
}